// Round 9
// baseline (44.537 us; speedup 1.0000x reference)
//
#include <hip/hip_runtime.h>
#include <hip/hip_bf16.h>

// ---------------------------------------------------------------------------
// Metric_Loss: two fused (X X^T/128 -> exp(1+.) -> row-sum) passes + pair combine.
// B=8192, E=128, P=4096.  Output: scalar f32 = metric_tt + metric_st.
//
// Round 9: one-barrier ring-3 choreography. MX-fp8 GEMM (R8 math) but the
// per-tile sync collapses from {vmcnt;bar; compute; lgkm;bar} to a single
// {lgkm0; vmcnt(4); bar} per tile: ring of 3 LDS buffers gives the
// write-after-read hazard one-iteration slack, and A-frags live in registers
// (loaded straight from global, L2-hot) so there is no A buffer at all.
// LDS 24KB -> 6 blocks/CU; stage of tile idx+2 issued at iter start stays in
// flight across MFMA+epilogue (vmcnt(4) = 2 stage loads + 2 atomics).
//
// ws layout:
//   [0, 1MB)        Xt fp8    [8192][128]   scaled by sqrt(log2e/128)
//   [1MB, 2MB)      Xm fp8    [8192][128]   (mixed: even=text, odd=shape[r>>1])
//   [2MB, 2MB+64KB) R f32     [2][8192]     row sums of exp(1+D)
// ---------------------------------------------------------------------------

#define B_ROWS 8192
#define E_COLS 128
#define P_PAIRS 4096
#define NSTRIP 128              // 64-row strips
#define NH 8                    // h-splits per strip

using f32x4 = __attribute__((ext_vector_type(4))) float;
using i32x8 = __attribute__((ext_vector_type(8))) int;

// sqrt(log2(e)/128): MFMA yields acc = D*log2(e); exp(1+D) = e * exp2(acc)
#define BF_SCALE 0.106164482742544f
#define EULER    2.718281828459045f
#define SCALE1   0x7f            // E8M0 exponent 127 -> 2^0 (unit scale)

// --------------------------- conversion kernel -----------------------------
__device__ __forceinline__ unsigned pk4_fp8(float a, float b, float c, float d) {
    unsigned v = 0;
    v = __builtin_amdgcn_cvt_pk_fp8_f32(a * BF_SCALE, b * BF_SCALE, v, false);
    v = __builtin_amdgcn_cvt_pk_fp8_f32(c * BF_SCALE, d * BF_SCALE, v, true);
    return v;
}

__global__ void convert_kernel(const float* __restrict__ text,
                               const float* __restrict__ shape,
                               unsigned* __restrict__ Xt,     // fp8 x4 per word
                               unsigned* __restrict__ Xm,
                               float* __restrict__ R,
                               float* __restrict__ out) {
    int idx = blockIdx.x * blockDim.x + threadIdx.x;     // 4 elements per thread
    if (idx < 4096) {                                    // zero R (2*8192 f32)
        float4 z; z.x = z.y = z.z = z.w = 0.f;
        ((float4*)R)[idx] = z;
    }
    if (idx == 0) *out = 0.f;
    int e = idx * 4;
    if (e >= B_ROWS * E_COLS) return;
    float4 t = *(const float4*)(text + e);
    unsigned tp = pk4_fp8(t.x, t.y, t.z, t.w);
    Xt[idx] = tp;
    int row = e >> 7;
    if (row & 1) {
        int col = e & 127;
        float4 s = *(const float4*)(shape + (row >> 1) * E_COLS + col);
        Xm[idx] = pk4_fp8(s.x, s.y, s.z, s.w);
    } else {
        Xm[idx] = tp;
    }
}

// --------------------------- fused GEMM + rowsum (MX-fp8, ring-3) ----------
__device__ __forceinline__ int lds_off(int row, int k0) {
    return (row << 7) + (k0 ^ ((row & 7) << 4));
}

// K=128 fragment from swizzled LDS: 32 contiguous fp8 at (row, k32).
__device__ __forceinline__ i32x8 load_frag32(const char* base, int row, int k32) {
    union { i32x8 v; int4 h[2]; } u;
    u.h[0] = *(const int4*)(base + lds_off(row, k32));
    u.h[1] = *(const int4*)(base + lds_off(row, k32 + 16));
    return u.v;
}

// K=128 fragment straight from global (row-major, unswizzled).
__device__ __forceinline__ i32x8 load_frag32_g(const char* rowbase, int k32) {
    union { i32x8 v; int4 h[2]; } u;
    u.h[0] = *(const int4*)(rowbase + k32);
    u.h[1] = *(const int4*)(rowbase + k32 + 16);
    return u.v;
}

// Stage one 64x128 fp8 tile (8KB): 2 iters of 256 threads x 16B.
__device__ __forceinline__ void stage8k(const char* gsrc, char* ldst, int tid) {
#pragma unroll
    for (int it = 0; it < 2; ++it) {
        int L   = it * 4096 + tid * 16;
        int row = L >> 7;
        int cb  = L & 127;
        int src = (row << 7) + (cb ^ ((row & 7) << 4));
        __builtin_amdgcn_global_load_lds(
            (const __attribute__((address_space(1))) void*)(gsrc + src),
            (__attribute__((address_space(3))) void*)(ldst + L), 16, 0, 0);
    }
}

// Block = (strip bm in 0..127, split h in 0..7, layer l). Strip = 64 A-rows.
// Tiles (bm, bn=(bm+t)&127): t in {1..63} each unordered pair once; t==64
// gated bm<64 (h==0); t==0 diagonal (h==0, from global). Wave: 32x32 quadrant.
__launch_bounds__(256, 6)
__global__ void gemm_rowsum_kernel(const unsigned char* __restrict__ Xt,
                                   const unsigned char* __restrict__ Xm,
                                   float* __restrict__ R) {
    const int bm = blockIdx.x, h = blockIdx.y, l = blockIdx.z;
    const char* gX = (const char*)(l ? Xm : Xt);

    __shared__ __align__(16) char bufs[3][64 * 128];
    const int tid = threadIdx.x;

    const int t0 = (h == 0) ? NH : h;
    const int N  = (h == 0) ? (bm < 64 ? 8 : 7) : 8;     // off-diag tile count

    // ---- prologue: stage tiles 0,1 into ring ----
    stage8k(gX + (size_t)((bm + t0) & 127) * 8192, bufs[0], tid);
    stage8k(gX + (size_t)((bm + t0 + NH) & 127) * 8192, bufs[1], tid);

    const int lane = tid & 63;
    const int w  = tid >> 6;
    const int wr = w >> 1, wc = w & 1;
    const int rA0 = wr * 32 + (lane & 15);
    const int rB0 = wc * 32 + (lane & 15);
    const int k32 = (lane >> 4) * 32;            // byte offset of lane's K-slice

    // ---- A fragments straight from global (L2-hot, one time) ----
    const char* Ag = gX + (size_t)bm * 8192;
    i32x8 afr[2];
    afr[0] = load_frag32_g(Ag + (size_t)rA0 * 128, k32);
    afr[1] = load_frag32_g(Ag + (size_t)(rA0 + 16) * 128, k32);

    float s_r[2][4] = {{0.f}};                   // persistent row partials [m][j]

    // ---- diagonal tile (h==0): B-frags from global too; rows only ----
    if (h == 0) {
        i32x8 b0 = load_frag32_g(Ag + (size_t)rB0 * 128, k32);
        i32x8 b1 = load_frag32_g(Ag + (size_t)(rB0 + 16) * 128, k32);
        f32x4 acc[2][2] = {};
        acc[0][0] = __builtin_amdgcn_mfma_scale_f32_16x16x128_f8f6f4(
            afr[0], b0, acc[0][0], 0, 0, 0, SCALE1, 0, SCALE1);
        acc[0][1] = __builtin_amdgcn_mfma_scale_f32_16x16x128_f8f6f4(
            afr[0], b1, acc[0][1], 0, 0, 0, SCALE1, 0, SCALE1);
        acc[1][0] = __builtin_amdgcn_mfma_scale_f32_16x16x128_f8f6f4(
            afr[1], b0, acc[1][0], 0, 0, 0, SCALE1, 0, SCALE1);
        acc[1][1] = __builtin_amdgcn_mfma_scale_f32_16x16x128_f8f6f4(
            afr[1], b1, acc[1][1], 0, 0, 0, SCALE1, 0, SCALE1);
#pragma unroll
        for (int m = 0; m < 2; ++m)
#pragma unroll
            for (int n = 0; n < 2; ++n)
#pragma unroll
                for (int j = 0; j < 4; ++j)
                    s_r[m][j] += __builtin_amdgcn_exp2f(acc[m][n][j]);
    }

    // ---- all stage-loads landed (own wave), then all waves ----
    asm volatile("s_waitcnt vmcnt(0)" ::: "memory");
    __builtin_amdgcn_s_barrier();

    // ---- one-barrier ring-3 main loop ----
    for (int idx = 0; idx < N; ++idx) {
        // stage tile idx+2 (overwrites buffer read at iter idx-1; safe after
        // the barrier that ended iter idx-1)
        if (idx + 2 < N)
            stage8k(gX + (size_t)((bm + t0 + NH * (idx + 2)) & 127) * 8192,
                    bufs[(idx + 2) % 3], tid);

        const char* lsrc = bufs[idx % 3];
        i32x8 bfr[2];
        bfr[0] = load_frag32(lsrc, rB0, k32);
        bfr[1] = load_frag32(lsrc, rB0 + 16, k32);

        f32x4 acc[2][2] = {};
        __builtin_amdgcn_s_setprio(1);
        acc[0][0] = __builtin_amdgcn_mfma_scale_f32_16x16x128_f8f6f4(
            afr[0], bfr[0], acc[0][0], 0, 0, 0, SCALE1, 0, SCALE1);
        acc[0][1] = __builtin_amdgcn_mfma_scale_f32_16x16x128_f8f6f4(
            afr[0], bfr[1], acc[0][1], 0, 0, 0, SCALE1, 0, SCALE1);
        acc[1][0] = __builtin_amdgcn_mfma_scale_f32_16x16x128_f8f6f4(
            afr[1], bfr[0], acc[1][0], 0, 0, 0, SCALE1, 0, SCALE1);
        acc[1][1] = __builtin_amdgcn_mfma_scale_f32_16x16x128_f8f6f4(
            afr[1], bfr[1], acc[1][1], 0, 0, 0, SCALE1, 0, SCALE1);
        __builtin_amdgcn_s_setprio(0);

        // ---- epilogue: rows -> regs, cols -> shuffle + atomics ----
        const int bn = (bm + t0 + NH * idx) & 127;
        float s_c[2] = {0.f, 0.f};
#pragma unroll
        for (int m = 0; m < 2; ++m)
#pragma unroll
            for (int n = 0; n < 2; ++n)
#pragma unroll
                for (int j = 0; j < 4; ++j) {
                    float e2 = __builtin_amdgcn_exp2f(acc[m][n][j]);
                    s_r[m][j] += e2;
                    s_c[n] += e2;
                }
#pragma unroll
        for (int n = 0; n < 2; ++n) {
            float v = s_c[n];
            v += __shfl_xor(v, 16, 64);
            v += __shfl_xor(v, 32, 64);
            if (lane < 16) {
                int gcol = bn * 64 + wc * 32 + n * 16 + lane;
                atomicAdd(&R[l * B_ROWS + gcol], EULER * v);
            }
        }

        // ---- single combined sync: my ds_reads done (overwrite safety) +
        //      tile idx+1 landed (vmcnt(4) = stage idx+2 (2) + atomics (2)) ----
        if (idx + 1 < N) {
            asm volatile("s_waitcnt lgkmcnt(0)" ::: "memory");
            asm volatile("s_waitcnt vmcnt(4)" ::: "memory");
            __builtin_amdgcn_s_barrier();
        }
    }

    // ---- final row reduction (once per block) ----
#pragma unroll
    for (int m = 0; m < 2; ++m)
#pragma unroll
        for (int j = 0; j < 4; ++j) {
            float v = s_r[m][j];
            v += __shfl_xor(v, 1, 64);
            v += __shfl_xor(v, 2, 64);
            v += __shfl_xor(v, 4, 64);
            v += __shfl_xor(v, 8, 64);
            if ((lane & 15) == 0) {
                int grow = bm * 64 + wr * 32 + m * 16 + (lane >> 4) * 4 + j;
                atomicAdd(&R[l * B_ROWS + grow], EULER * v);
            }
        }
}

// --------------------------- finalize --------------------------------------
__global__ void finalize_kernel(const float* __restrict__ text,
                                const float* __restrict__ shape,
                                const float* __restrict__ R,
                                float* __restrict__ out) {
    const int tid = threadIdx.x;
    const int lane = tid & 63;
    const int w = tid >> 6;
    const int waveGlobal = blockIdx.x * 4 + w;   // 2048 waves total
    const float inv128 = 0.0078125f;
    float accum = 0.f;

    for (int task = waveGlobal; task < 2 * P_PAIRS; task += 2048) {
        int l = task >> 12;
        int p = task & (P_PAIRS - 1);
        const float* a = text + (2 * p) * E_COLS;                       // even row: always text
        const float* b = l ? (shape + p * E_COLS) : (text + (2 * p + 1) * E_COLS);
        float2 av = *(const float2*)(a + lane * 2);
        float2 bv = *(const float2*)(b + lane * 2);
        float dii = av.x * av.x + av.y * av.y;
        float djj = bv.x * bv.x + bv.y * bv.y;
        float dij = av.x * bv.x + av.y * bv.y;
#pragma unroll
        for (int sh = 1; sh < 64; sh <<= 1) {
            dii += __shfl_xor(dii, sh, 64);
            djj += __shfl_xor(djj, sh, 64);
            dij += __shfl_xor(dij, sh, 64);
        }
        if (lane == 0) {
            float Dii = dii * inv128, Djj = djj * inv128, Dij = dij * inv128;
            float S = R[l * B_ROWS + 2 * p] + R[l * B_ROWS + 2 * p + 1]
                    - (__expf(1.f + Dii) + 2.f * __expf(1.f + Dij) + __expf(1.f + Djj));
            float J = __logf(S) - Dij;
            accum += 0.5f * J * J * (1.0f / (float)P_PAIRS);
        }
    }

    __shared__ float red[4];
    if (lane == 0) red[w] = accum;
    __syncthreads();
    if (tid == 0) {
        atomicAdd(out, red[0] + red[1] + red[2] + red[3]);
    }
}

// --------------------------- launch ----------------------------------------
extern "C" void kernel_launch(void* const* d_in, const int* in_sizes, int n_in,
                              void* d_out, int out_size, void* d_ws, size_t ws_size,
                              hipStream_t stream) {
    const float* text  = (const float*)d_in[0];
    const float* shape = (const float*)d_in[1];
    float* out = (float*)d_out;
    char* ws = (char*)d_ws;

    unsigned char* Xt = (unsigned char*)ws;
    unsigned char* Xm = (unsigned char*)(ws + 1u * 1024u * 1024u);
    float* R = (float*)(ws + 2u * 1024u * 1024u);

    convert_kernel<<<(B_ROWS * E_COLS / 4 + 255) / 256, 256, 0, stream>>>(
        text, shape, (unsigned*)Xt, (unsigned*)Xm, R, out);

    dim3 grid(NSTRIP, NH, 2);                    // 128 strips x 8 splits x 2 layers
    gemm_rowsum_kernel<<<grid, 256, 0, stream>>>(Xt, Xm, R);

    finalize_kernel<<<512, 256, 0, stream>>>(text, shape, R, out);
}